// Round 10
// baseline (381.762 us; speedup 1.0000x reference)
//
#include <hip/hip_runtime.h>
#include <hip/hip_bf16.h>
#include <cstdint>
#include <cstddef>

// Problem constants
#define BMC 32    // B*M
#define NNODE 1024
#define DIN 128
#define PPROJ 64
#define NCLUS 10
#define FOUT 128
#define KNB 10

typedef _Float16 half8 __attribute__((ext_vector_type(8)));
typedef float f32x4 __attribute__((ext_vector_type(4)));

// Inputs: fp32 (probe-confirmed). Output: fp32. Internals fp32 except:
//  - Z stored as fp16 split pair Zh/Zl (lo scaled x2048) for MFMA Gram
//  - Ek bf16 (overlays dead Zh/Zl region after k_topk)
// X_trans fp32 (16 MB) lives in d_out; k_final overwrites d_out with output.
static const size_t OFF_Z    = 0;          // words [0,1048576): Zh fp16; [1048576,2097152): Zl fp16
static const size_t OFF_SQ   = 2097152;    // 32,768     ||Z||^2 fp32
static const size_t OFF_HC   = 2129920;    // 327,680    softmax cluster H fp32
static const size_t OFF_IDX  = 2457600;    // 327,680    (int) knn indices
static const size_t OFF_CNT  = 2785280;    // 32,768     (int) edge in-degree  [ZEROED]
static const size_t OFF_FILL = 2818048;    // 32,768     (int) CSR fill ptrs   [ZEROED]
static const size_t OFF_EC   = 2850816;    // 40,960     cluster edge feats    [ZEROED]
static const size_t OFF_DCV  = 2891776;    // 320        cluster edge degrees  [ZEROED]
static const size_t OFF_OFFS = 2892096;    // 32,768     (int) CSR offsets
static const size_t OFF_ADJ  = 2924864;    // 327,680    (int) CSR adjacency
static const size_t OFF_FLAG = 3252544;    // 1          (int) input-dtype flag
static const size_t OFF_END  = 3252608;
static const size_t ZERO_N   = OFF_OFFS - OFF_CNT;

__device__ __forceinline__ float bfu(unsigned int lo16) {
    return __uint_as_float(lo16 << 16);
}
__device__ __forceinline__ float bfhi(unsigned int w) {
    return __uint_as_float(w & 0xffff0000u);
}
__device__ __forceinline__ float ldf(const void* p, size_t i, bool isbf) {
    return isbf ? bfu((unsigned int)((const unsigned short*)p)[i])
                : ((const float*)p)[i];
}
__device__ __forceinline__ unsigned short f2bf(float v) {
    __hip_bfloat16 h = __float2bfloat16(v);
    return *(unsigned short*)&h;
}

// ---------------------------------------------------------------------------
__global__ __launch_bounds__(256) void k_probe(const unsigned int* __restrict__ xw,
                                               int* __restrict__ flag) {
    __shared__ int red[256];
    int t = threadIdx.x;
    int cnt = 0;
    for (int i = t; i < 1024; i += 256) {
        float b = bfu(xw[i] & 0xffffu);
        float ab = fabsf(b);
        if (ab > 9.5e-7f && ab < 1.0e6f) cnt++;
    }
    red[t] = cnt;
    __syncthreads();
    for (int off = 128; off > 0; off >>= 1) {
        if (t < off) red[t] += red[t + off];
        __syncthreads();
    }
    if (t == 0) flag[0] = (red[0] >= 700) ? 1 : 0;
}

__global__ __launch_bounds__(256) void k_zero(float* __restrict__ p, int n) {
    int i = blockIdx.x * 256 + threadIdx.x;
    if (i < n) p[i] = 0.0f;
}

// ---------------------------------------------------------------------------
// Kernel 1: Z = x_flat @ Wp^T + b ; sq = ||Z||^2 ; Hc = softmax(Z @ C^T)
// (unchanged — passed R7..R9)
// ---------------------------------------------------------------------------
__global__ __launch_bounds__(256) void k_proj(const void* __restrict__ x,
                                              const void* __restrict__ Wp,
                                              const void* __restrict__ Wpb,
                                              const void* __restrict__ Cm,
                                              const int* __restrict__ flag,
                                              _Float16* __restrict__ Zh,
                                              _Float16* __restrict__ Zl,
                                              float* __restrict__ sqv,
                                              float* __restrict__ Hc) {
    __shared__ float xs[32][132];
    __shared__ float wpT[128][65];
    __shared__ float cs[10][64];
    __shared__ float zs[32][68];

    const bool isbf = (flag[0] != 0);
    int tid = threadIdx.x;
    int bi  = blockIdx.x;
    int bm  = bi >> 5;
    int n0  = (bi & 31) << 5;
    int b   = bm >> 3, m = bm & 7;

    if (isbf) {
        const unsigned short* xp = (const unsigned short*)x;
        for (int e = tid; e < 512; e += 256) {
            int r = e >> 4, h = e & 15;
            uint4 u = *(const uint4*)(xp + ((((size_t)b * NNODE + n0 + r) * 8 + m) * DIN + h * 8));
            int c = h * 8;
            xs[r][c+0] = bfu(u.x & 0xffffu); xs[r][c+1] = bfhi(u.x);
            xs[r][c+2] = bfu(u.y & 0xffffu); xs[r][c+3] = bfhi(u.y);
            xs[r][c+4] = bfu(u.z & 0xffffu); xs[r][c+5] = bfhi(u.z);
            xs[r][c+6] = bfu(u.w & 0xffffu); xs[r][c+7] = bfhi(u.w);
        }
    } else {
        const float* xp = (const float*)x;
        for (int e = tid; e < 1024; e += 256) {
            int r = e >> 5, q = e & 31;
            *(float4*)&xs[r][q * 4] =
                *(const float4*)(xp + ((((size_t)b * NNODE + n0 + r) * 8 + m) * DIN + q * 4));
        }
    }
    for (int e = tid; e < 8192; e += 256) {
        int p = e >> 7, d = e & 127;
        wpT[d][p] = ldf(Wp, (size_t)p * 128 + d, isbf);
    }
    for (int e = tid; e < 640; e += 256) cs[e >> 6][e & 63] = ldf(Cm, e, isbf);
    __syncthreads();

    int rg = tid >> 6, p = tid & 63;
    float acc[8] = {0.f,0.f,0.f,0.f,0.f,0.f,0.f,0.f};
    for (int d4 = 0; d4 < 32; ++d4) {
        float w0 = wpT[d4*4+0][p], w1 = wpT[d4*4+1][p];
        float w2 = wpT[d4*4+2][p], w3 = wpT[d4*4+3][p];
#pragma unroll
        for (int j = 0; j < 8; ++j) {
            float4 xv = *(const float4*)&xs[rg*8+j][d4*4];
            acc[j] += xv.x*w0 + xv.y*w1 + xv.z*w2 + xv.w*w3;
        }
    }
    float bias = ldf(Wpb, p, isbf);
#pragma unroll
    for (int j = 0; j < 8; ++j) {
        float v = acc[j] + bias;
        zs[rg*8+j][p] = v;
        size_t off = ((size_t)bm * NNODE + n0 + rg*8 + j) * 64 + p;
        _Float16 h = (_Float16)v;
        _Float16 l = (_Float16)((v - (float)h) * 2048.0f);
        Zh[off] = h;
        Zl[off] = l;
    }
    __syncthreads();

    int row = tid >> 3, slot = tid & 7;
    int d0 = slot * 8;
    float sp = 0.f;
#pragma unroll
    for (int dd = 0; dd < 8; ++dd) { float z = zs[row][d0+dd]; sp += z * z; }
#pragma unroll
    for (int mm = 1; mm < 8; mm <<= 1) sp += __shfl_xor(sp, mm, 8);
    size_t g = (size_t)bm * NNODE + n0 + row;
    if (slot == 0) sqv[g] = sp;

    float sc[10];
#pragma unroll
    for (int c = 0; c < 10; ++c) {
        float pa = 0.f;
#pragma unroll
        for (int dd = 0; dd < 8; ++dd) pa += zs[row][d0+dd] * cs[c][d0+dd];
#pragma unroll
        for (int mm = 1; mm < 8; mm <<= 1) pa += __shfl_xor(pa, mm, 8);
        sc[c] = pa;
    }
    float mx = sc[0];
#pragma unroll
    for (int c = 1; c < 10; ++c) mx = fmaxf(mx, sc[c]);
    float ssum = 0.f;
#pragma unroll
    for (int c = 0; c < 10; ++c) { sc[c] = expf(sc[c] - mx); ssum += sc[c]; }
    float inv = 1.0f / ssum;
#pragma unroll
    for (int c = 0; c < 10; ++c)
        if ((c & 7) == slot) Hc[g * 10 + c] = sc[c] * inv;
}

// ---------------------------------------------------------------------------
// Kernel 2: X_trans = x_flat @ Theta^T + b  -> fp32 in d_out (unchanged)
// ---------------------------------------------------------------------------
__global__ __launch_bounds__(256) void k_theta(const void* __restrict__ x,
                                               const void* __restrict__ Th,
                                               const void* __restrict__ Thb,
                                               const int* __restrict__ flag,
                                               float* __restrict__ Xt) {
    __shared__ float xs[32][132];
    __shared__ float thT[64][132];

    const bool isbf = (flag[0] != 0);
    int tid = threadIdx.x;
    int bi  = blockIdx.x;
    int bm  = bi >> 5;
    int n0  = (bi & 31) << 5;
    int b   = bm >> 3, m = bm & 7;

    if (isbf) {
        const unsigned short* xp = (const unsigned short*)x;
        for (int e = tid; e < 512; e += 256) {
            int r = e >> 4, h = e & 15;
            uint4 u = *(const uint4*)(xp + ((((size_t)b * NNODE + n0 + r) * 8 + m) * DIN + h * 8));
            int c = h * 8;
            xs[r][c+0] = bfu(u.x & 0xffffu); xs[r][c+1] = bfhi(u.x);
            xs[r][c+2] = bfu(u.y & 0xffffu); xs[r][c+3] = bfhi(u.y);
            xs[r][c+4] = bfu(u.z & 0xffffu); xs[r][c+5] = bfhi(u.z);
            xs[r][c+6] = bfu(u.w & 0xffffu); xs[r][c+7] = bfhi(u.w);
        }
    } else {
        const float* xp = (const float*)x;
        for (int e = tid; e < 1024; e += 256) {
            int r = e >> 5, q = e & 31;
            *(float4*)&xs[r][q * 4] =
                *(const float4*)(xp + ((((size_t)b * NNODE + n0 + r) * 8 + m) * DIN + q * 4));
        }
    }

    int rg = tid >> 7, f = tid & 127;
    float acc[16];
#pragma unroll
    for (int j = 0; j < 16; ++j) acc[j] = 0.f;

    for (int kc = 0; kc < 2; ++kc) {
        __syncthreads();
        for (int e = tid; e < 8192; e += 256) {
            int ff = e >> 6, dk = e & 63;
            thT[dk][ff] = ldf(Th, (size_t)ff * 128 + kc * 64 + dk, isbf);
        }
        __syncthreads();
        for (int dk4 = 0; dk4 < 16; ++dk4) {
            float w0 = thT[dk4*4+0][f], w1 = thT[dk4*4+1][f];
            float w2 = thT[dk4*4+2][f], w3 = thT[dk4*4+3][f];
            int dbase = kc * 64 + dk4 * 4;
#pragma unroll
            for (int j = 0; j < 16; ++j) {
                float4 xv = *(const float4*)&xs[rg*16+j][dbase];
                acc[j] += xv.x*w0 + xv.y*w1 + xv.z*w2 + xv.w*w3;
            }
        }
    }
    float bias = ldf(Thb, f, isbf);
#pragma unroll
    for (int j = 0; j < 16; ++j)
        Xt[((size_t)bm * NNODE + n0 + rg*16 + j) * 128 + f] = acc[j] + bias;
}

// ---------------------------------------------------------------------------
// Kernel 3 v3: fused Gram + top-K, NO LDS B-staging.
// B-fragments + sq read directly from global (Zh/Zl per bm = 256 KB, L2-hot,
// shared by 64 blocks). LDS holds only the 5 KB score-transpose tile ->
// ~8 blocks/CU residency. Math bit-identical to R8/R9 (passed).
// ---------------------------------------------------------------------------
__global__ __launch_bounds__(256) void k_topk(const _Float16* __restrict__ Zh,
                                              const _Float16* __restrict__ Zl,
                                              const float* __restrict__ sqv,
                                              int* __restrict__ idxo,
                                              int* __restrict__ cnt) {
    __shared__ float ST[64 * 20];   // scores [col][row(16)+pad]

    int tid = threadIdx.x;
    int bi  = blockIdx.x;
    int bm  = bi >> 6;
    int n0  = (bi & 63) << 4;       // 16 rows per block
    const _Float16* Zhb = Zh + (size_t)bm * NNODE * 64;
    const _Float16* Zlb = Zl + (size_t)bm * NNODE * 64;
    const float*    sqb = sqv + (size_t)bm * NNODE;

    int lane = tid & 63, wave = tid >> 6;
    int m16 = lane & 15, quad = lane >> 4;

    // A fragments: block's 16 rows (same for all 4 waves), K=64, hi+lo.
    half8 ah0, ah1, al0, al1;
    {
        size_t ab = (size_t)(n0 + m16) * 64 + quad * 8;
        ah0 = *(const half8*)(Zhb + ab);
        ah1 = *(const half8*)(Zhb + ab + 32);
        al0 = *(const half8*)(Zlb + ab);
        al1 = *(const half8*)(Zlb + ab + 32);
    }

    unsigned long long keys[10];
#pragma unroll
    for (int j = 0; j < 10; ++j) keys[j] = ~0ULL;

    int srow  = tid >> 4;   // 0..15: row within block
    int sslot = tid & 15;   // 16 threads per row

    for (int t = 0; t < 16; ++t) {
        int j0 = t << 6;
        int cl = wave * 16 + m16;               // col within 64-col tile
        size_t cb = (size_t)(j0 + cl) * 64 + quad * 8;
        half8 bh0 = *(const half8*)(Zhb + cb);
        half8 bh1 = *(const half8*)(Zhb + cb + 32);
        half8 bl0 = *(const half8*)(Zlb + cb);
        half8 bl1 = *(const half8*)(Zlb + cb + 32);
        float sqc = sqb[j0 + cl];

        f32x4 acc  = {0.f, 0.f, 0.f, 0.f};
        f32x4 accx = {0.f, 0.f, 0.f, 0.f};
        acc  = __builtin_amdgcn_mfma_f32_16x16x32_f16(ah0, bh0, acc, 0, 0, 0);
        acc  = __builtin_amdgcn_mfma_f32_16x16x32_f16(ah1, bh1, acc, 0, 0, 0);
        accx = __builtin_amdgcn_mfma_f32_16x16x32_f16(al0, bh0, accx, 0, 0, 0);
        accx = __builtin_amdgcn_mfma_f32_16x16x32_f16(ah0, bl0, accx, 0, 0, 0);
        accx = __builtin_amdgcn_mfma_f32_16x16x32_f16(al1, bh1, accx, 0, 0, 0);
        accx = __builtin_amdgcn_mfma_f32_16x16x32_f16(ah1, bl1, accx, 0, 0, 0);
        f32x4 sc;
#pragma unroll
        for (int r = 0; r < 4; ++r) {
            float g = acc[r] + accx[r] * (1.0f / 2048.0f);
            sc[r] = fmaf(-2.0f, g, sqc);
        }

        __syncthreads();   // previous tile's selection reads done
        // C/D layout: col=lane&15 (cl), rows quad*4+r -> transposed store
        *(f32x4*)&ST[cl * 20 + quad * 4] = sc;
        __syncthreads();   // scores visible

        // selection: 4 cols per thread (16 threads/row)
#pragma unroll
        for (int i = 0; i < 4; ++i) {
            int c = sslot + (i << 4);
            float v = ST[c * 20 + srow];
            unsigned int bits = __float_as_uint(v);
            unsigned int s = (bits & 0x80000000u) ? ~bits : (bits | 0x80000000u);
            unsigned long long key =
                ((unsigned long long)s << 32) | (unsigned int)(j0 + c);
            if (key < keys[9]) {
                keys[9] = key;
#pragma unroll
                for (int j = 9; j > 0; --j) {
                    if (keys[j] < keys[j-1]) {
                        unsigned long long tk = keys[j];
                        keys[j] = keys[j-1]; keys[j-1] = tk;
                    }
                }
            }
        }
    }

    // merge 16 sorted lists per row: 10 rounds of width-16 min-extraction
    size_t gr = (size_t)bm * NNODE + n0 + srow;
    for (int it = 0; it < 10; ++it) {
        unsigned long long mine = keys[0];
        unsigned long long best = mine;
#pragma unroll
        for (int mm = 1; mm < 16; mm <<= 1) {
            unsigned long long o = __shfl_xor(best, mm, 16);
            if (o < best) best = o;
        }
        if (best == mine) {
#pragma unroll
            for (int j = 0; j < 9; ++j) keys[j] = keys[j+1];
            keys[9] = ~0ULL;
            int col = (int)(best & 0xFFFFFFFFu);
            idxo[gr * KNB + it] = col;
            atomicAdd(&cnt[bm * NNODE + col], 1);
        }
    }
}

// ---------------------------------------------------------------------------
// CSR build (unchanged)
// ---------------------------------------------------------------------------
__global__ __launch_bounds__(256) void k_scan(const int* __restrict__ cnt,
                                              int* __restrict__ offs) {
    __shared__ int part[256];
    int bm = blockIdx.x, t = threadIdx.x;
    int base = bm * 1024 + t * 4;
    int c0 = cnt[base], c1 = cnt[base+1], c2 = cnt[base+2], c3 = cnt[base+3];
    int ps = c0 + c1 + c2 + c3;
    part[t] = ps;
    __syncthreads();
    for (int off = 1; off < 256; off <<= 1) {
        int add = (t >= off) ? part[t - off] : 0;
        __syncthreads();
        part[t] += add;
        __syncthreads();
    }
    int e0 = part[t] - ps;
    int gb = bm * (NNODE * KNB);
    offs[base]   = gb + e0;
    offs[base+1] = gb + e0 + c0;
    offs[base+2] = gb + e0 + c0 + c1;
    offs[base+3] = gb + e0 + c0 + c1 + c2;
}

__global__ __launch_bounds__(256) void k_fill(const int* __restrict__ idxb,
                                              const int* __restrict__ offs,
                                              int* __restrict__ fill,
                                              int* __restrict__ adj) {
    int i = blockIdx.x * 256 + threadIdx.x;
    int g = i / 10;
    int bm = g >> 10;
    int e  = idxb[i];
    int eg = (bm << 10) + e;
    int pos = atomicAdd(&fill[eg], 1);
    adj[offs[eg] + pos] = g;
}

// ---------------------------------------------------------------------------
// kNN edge gather v2 (unchanged from R9 — fixed the latency bottleneck)
// ---------------------------------------------------------------------------
__global__ __launch_bounds__(256) void k_edge(const float* __restrict__ Xt,
                                              const int* __restrict__ offs,
                                              const int* __restrict__ cnt,
                                              const int* __restrict__ adj,
                                              unsigned short* __restrict__ Ek) {
    int tid = threadIdx.x;
    int e = blockIdx.x * 8 + (tid >> 5);
    int l = tid & 31;
    int start = offs[e];
    int num = cnt[e];
    float4 acc = {0.f, 0.f, 0.f, 0.f};
    int i = 0;
    for (; i + 1 < num; i += 2) {
        int g0 = adj[start + i];
        int g1 = adj[start + i + 1];
        float4 a = *(const float4*)(Xt + (size_t)g0 * 128 + l * 4);
        float4 b = *(const float4*)(Xt + (size_t)g1 * 128 + l * 4);
        acc.x += a.x + b.x; acc.y += a.y + b.y;
        acc.z += a.z + b.z; acc.w += a.w + b.w;
    }
    if (i < num) {
        int g0 = adj[start + i];
        float4 a = *(const float4*)(Xt + (size_t)g0 * 128 + l * 4);
        acc.x += a.x; acc.y += a.y; acc.z += a.z; acc.w += a.w;
    }
    float scale = (num > 0) ? 1.0f / (float)num : 0.0f;
    ushort4 o;
    o.x = f2bf(acc.x * scale);
    o.y = f2bf(acc.y * scale);
    o.z = f2bf(acc.z * scale);
    o.w = f2bf(acc.w * scale);
    *(ushort4*)(Ek + (size_t)e * 128 + l * 4) = o;
}

// ---------------------------------------------------------------------------
// Cluster edges v2: 1024 blocks (32-node chunks), Hc chunk staged in LDS
// (broadcast reads), 2-way unrolled Xt loop for MLP.
// ---------------------------------------------------------------------------
__global__ __launch_bounds__(256) void k_clus(const float* __restrict__ Xt,
                                              const float* __restrict__ Hc,
                                              float* __restrict__ Ec,
                                              float* __restrict__ Dcv) {
    __shared__ float hs[320];   // 32 nodes x 10 clusters
    int tid = threadIdx.x;
    int bm = blockIdx.x >> 5;
    int ch = blockIdx.x & 31;
    int f = tid & 127;
    int h = tid >> 7;
    int c0 = h * 5;
    int n0 = ch * 32;

    for (int e = tid; e < 320; e += 256)
        hs[e] = Hc[((size_t)bm * NNODE + n0) * 10 + e];
    __syncthreads();

    float acc[5]  = {0.f,0.f,0.f,0.f,0.f};
    const float* xb = Xt + ((size_t)bm * NNODE + n0) * 128 + f;
    for (int n = 0; n < 32; n += 2) {
        float xv0 = xb[(size_t)n * 128];
        float xv1 = xb[(size_t)(n + 1) * 128];
#pragma unroll
        for (int j = 0; j < 5; ++j) {
            acc[j] += hs[n * 10 + c0 + j] * xv0
                    + hs[(n + 1) * 10 + c0 + j] * xv1;
        }
    }
#pragma unroll
    for (int j = 0; j < 5; ++j)
        atomicAdd(&Ec[((size_t)bm * 10 + c0 + j) * 128 + f], acc[j]);
    if (f == 0) {
#pragma unroll
        for (int j = 0; j < 5; ++j) {
            float d = 0.f;
            for (int n = 0; n < 32; ++n) d += hs[n * 10 + c0 + j];
            atomicAdd(&Dcv[bm * 10 + c0 + j], d);
        }
    }
}

__global__ __launch_bounds__(256) void k_escale(float* __restrict__ Ec,
                                                const float* __restrict__ Dcv) {
    int i = blockIdx.x * 256 + threadIdx.x;
    float d = Dcv[i >> 7];
    Ec[i] = (d > 0.f) ? Ec[i] / d : 0.f;
}

// ---------------------------------------------------------------------------
// Final v2 (unchanged from R9)
// ---------------------------------------------------------------------------
__global__ __launch_bounds__(256) void k_final(const unsigned short* __restrict__ Ek,
                                               const float* __restrict__ Ec,
                                               const float* __restrict__ Hc,
                                               const int* __restrict__ idxb,
                                               float* __restrict__ out) {
    int tid = threadIdx.x;
    int g = blockIdx.x * 8 + (tid >> 5);
    int l = tid & 31;
    int bm = g >> 10, n = g & 1023;
    const int* ip = idxb + (size_t)g * 10;
    const unsigned short* ekb = Ek + ((size_t)bm << 10) * 128 + l * 4;

    float4 acc = {0.f, 0.f, 0.f, 0.f};
#pragma unroll
    for (int k = 0; k < 10; k += 2) {
        int e0 = ip[k], e1 = ip[k + 1];
        ushort4 u0 = *(const ushort4*)(ekb + (size_t)e0 * 128);
        ushort4 u1 = *(const ushort4*)(ekb + (size_t)e1 * 128);
        acc.x += bfu(u0.x) + bfu(u1.x);
        acc.y += bfu(u0.y) + bfu(u1.y);
        acc.z += bfu(u0.z) + bfu(u1.z);
        acc.w += bfu(u0.w) + bfu(u1.w);
    }
    const float* hp  = Hc + (size_t)g * 10;
    const float* ecp = Ec + (size_t)bm * 10 * 128 + l * 4;
#pragma unroll
    for (int c = 0; c < 10; ++c) {
        float hv = hp[c];
        float4 ec = *(const float4*)(ecp + c * 128);
        acc.x += hv * ec.x; acc.y += hv * ec.y;
        acc.z += hv * ec.z; acc.w += hv * ec.w;
    }
    float4 r;
    r.x = acc.x * (1.0f / 11.0f);
    r.y = acc.y * (1.0f / 11.0f);
    r.z = acc.z * (1.0f / 11.0f);
    r.w = acc.w * (1.0f / 11.0f);
    r.x = (r.x > 0.f) ? r.x : expm1f(r.x);
    r.y = (r.y > 0.f) ? r.y : expm1f(r.y);
    r.z = (r.z > 0.f) ? r.z : expm1f(r.z);
    r.w = (r.w > 0.f) ? r.w : expm1f(r.w);
    int b = bm >> 3, m = bm & 7;
    *(float4*)(out + (((size_t)b * NNODE + n) * 8 + m) * 128 + l * 4) = r;
}

// ---------------------------------------------------------------------------
extern "C" void kernel_launch(void* const* d_in, const int* in_sizes, int n_in,
                              void* d_out, int out_size, void* d_ws, size_t ws_size,
                              hipStream_t stream) {
    const void* x   = d_in[0];
    const void* Wp  = d_in[1];
    const void* Wpb = d_in[2];
    const void* Cm  = d_in[3];
    const void* Th  = d_in[4];
    const void* Thb = d_in[5];
    float* ws = (float*)d_ws;

    if (ws_size < OFF_END * sizeof(float)) return;

    _Float16* Zh = (_Float16*)(ws + OFF_Z);
    _Float16* Zl = (_Float16*)(ws + OFF_Z + 1048576);
    float* sqv  = ws + OFF_SQ;
    float* Hc   = ws + OFF_HC;
    int*   idxb = (int*)(ws + OFF_IDX);
    int*   cnt  = (int*)(ws + OFF_CNT);
    int*   fill = (int*)(ws + OFF_FILL);
    float* Ec   = ws + OFF_EC;
    float* Dcv  = ws + OFF_DCV;
    int*   offs = (int*)(ws + OFF_OFFS);
    int*   adj  = (int*)(ws + OFF_ADJ);
    int*   flag = (int*)(ws + OFF_FLAG);
    unsigned short* Ek = (unsigned short*)(ws + OFF_Z);  // overlays dead Zh/Zl
    float* Xt  = (float*)d_out;
    float* out = (float*)d_out;

    k_probe <<<1, 256, 0, stream>>>((const unsigned int*)x, flag);
    k_zero  <<<(int)((ZERO_N + 255) / 256), 256, 0, stream>>>(ws + OFF_CNT, (int)ZERO_N);
    k_proj  <<<1024, 256, 0, stream>>>(x, Wp, Wpb, Cm, flag, Zh, Zl, sqv, Hc);
    k_topk  <<<2048, 256, 0, stream>>>(Zh, Zl, sqv, idxb, cnt);
    k_scan  <<<32,   256, 0, stream>>>(cnt, offs);
    k_fill  <<<1280, 256, 0, stream>>>(idxb, offs, fill, adj);
    k_theta <<<1024, 256, 0, stream>>>(x, Th, Thb, flag, Xt);
    k_edge  <<<4096, 256, 0, stream>>>(Xt, offs, cnt, adj, Ek);
    k_clus  <<<1024, 256, 0, stream>>>(Xt, Hc, Ec, Dcv);
    k_escale<<<160,  256, 0, stream>>>(Ec, Dcv);
    k_final <<<4096, 256, 0, stream>>>(Ek, Ec, Hc, idxb, out);
}